// Round 1
// baseline (636.875 us; speedup 1.0000x reference)
//
#include <hip/hip_runtime.h>

#define NMAX 1024
#define BB   128
#define BINS 64
#define ROWS 32   // rows per block in degree kernel; N/ROWS = 32 chunks per batch

// Per block: one batch b, 32 consecutive rows. 256 threads, thread t owns
// columns 4t..4t+3 (one float4 per row). Row sums: wave shuffle-reduce +
// LDS combine across 4 waves, direct store. Col sums: private register
// accumulators over the 32 rows, then global atomicAdd (zero-skipped).
__global__ __launch_bounds__(256) void degree_kernel(
    const float* __restrict__ adj, const int* __restrict__ num_nodes,
    float* __restrict__ in_deg, float* __restrict__ out_deg)
{
    const int b     = blockIdx.x >> 5;   // 32 chunks per batch
    const int chunk = blockIdx.x & 31;
    const int n     = num_nodes[b];
    const int row0  = chunk * ROWS;
    if (row0 >= n) return;               // whole chunk is masked out

    const int t    = threadIdx.x;
    const int lane = t & 63;
    const int wave = t >> 6;
    const int j0   = t * 4;
    const bool act = (j0 < n);           // thread has at least one valid column

    // per-element column masks (handle n not multiple of 4)
    const float m0 = (j0 + 0 < n) ? 1.f : 0.f;
    const float m1 = (j0 + 1 < n) ? 1.f : 0.f;
    const float m2 = (j0 + 2 < n) ? 1.f : 0.f;
    const float m3 = (j0 + 3 < n) ? 1.f : 0.f;

    float c0 = 0.f, c1 = 0.f, c2 = 0.f, c3 = 0.f;  // column partial sums

    __shared__ float rowpart[ROWS][4];   // [row_in_chunk][wave]

    const int rows = min(ROWS, n - row0);
    const float4* base = (const float4*)(adj + ((size_t)b * NMAX + row0) * NMAX);

    for (int r = 0; r < rows; ++r) {
        float4 v = make_float4(0.f, 0.f, 0.f, 0.f);
        if (act) v = base[r * (NMAX / 4) + t];   // coalesced 16B/lane
        const float x0 = v.x * m0, x1 = v.y * m1, x2 = v.z * m2, x3 = v.w * m3;
        c0 += x0; c1 += x1; c2 += x2; c3 += x3;
        float s = (x0 + x1) + (x2 + x3);
        // wave64 reduce (all threads participate; inactive have s = 0)
        s += __shfl_down(s, 32);
        s += __shfl_down(s, 16);
        s += __shfl_down(s, 8);
        s += __shfl_down(s, 4);
        s += __shfl_down(s, 2);
        s += __shfl_down(s, 1);
        if (lane == 0) rowpart[r][wave] = s;
    }
    __syncthreads();

    if (t < rows) {
        const float s = rowpart[t][0] + rowpart[t][1] + rowpart[t][2] + rowpart[t][3];
        in_deg[b * NMAX + row0 + t] = s;   // unique row per block: plain store
    }

    if (act) {
        float* op = out_deg + b * NMAX + j0;
        if (c0 != 0.f) atomicAdd(op + 0, c0);
        if (c1 != 0.f) atomicAdd(op + 1, c1);
        if (c2 != 0.f) atomicAdd(op + 2, c2);
        if (c3 != 0.f) atomicAdd(op + 3, c3);
    }
}

// One block per (side, b). Triangle kernel with width = 1/spacing has
// support exactly [c_k - spacing, c_k + spacing] -> each degree value
// contributes to bins floor(d/spacing) and floor(d/spacing)+1 only.
// Score computed with the exact reference formula using the input arrays.
__global__ __launch_bounds__(256) void hist_kernel(
    const float* __restrict__ deg, const int* __restrict__ num_nodes,
    const float* __restrict__ centers, const float* __restrict__ widths,
    float* __restrict__ out)
{
    const int side = blockIdx.x >> 7;    // 0: in_deg, 1: out_deg
    const int b    = blockIdx.x & 127;

    __shared__ float hist[BINS];
    __shared__ float c[BINS];
    __shared__ float w[BINS];
    if (threadIdx.x < BINS) {
        hist[threadIdx.x] = 0.f;
        c[threadIdx.x] = centers[threadIdx.x];
        w[threadIdx.x] = widths[threadIdx.x];
    }
    __syncthreads();

    const int n = num_nodes[b];
    const float inv_sp = w[0];           // 1/spacing (uniform bins)
    const float* dp = deg + ((size_t)side * BB + b) * NMAX;

    for (int i = threadIdx.x; i < n; i += 256) {
        const float d   = dp[i];
        const float pos = d * inv_sp;
        const int   k0  = (int)floorf(pos);
        #pragma unroll
        for (int kk = 0; kk < 2; ++kk) {
            const int k = k0 + kk;
            if (k >= 0 && k < BINS) {
                const float s = 1.f - fabsf(d - c[k]) * w[k];
                if (s > 0.f) atomicAdd(&hist[k], s);
            }
        }
    }
    __syncthreads();

    if (threadIdx.x < BINS)
        out[((size_t)side * BB + b) * BINS + threadIdx.x] = hist[threadIdx.x];
}

extern "C" void kernel_launch(void* const* d_in, const int* in_sizes, int n_in,
                              void* d_out, int out_size, void* d_ws, size_t ws_size,
                              hipStream_t stream) {
    const float* adj       = (const float*)d_in[0];
    const int*   num_nodes = (const int*)d_in[1];
    const float* centers   = (const float*)d_in[2];
    const float* widths    = (const float*)d_in[3];
    float* out = (float*)d_out;

    float* deg = (float*)d_ws;                    // [2][BB][NMAX]: in_deg then out_deg
    const size_t deg_bytes = (size_t)2 * BB * NMAX * sizeof(float);

    hipMemsetAsync(d_ws, 0, deg_bytes, stream);   // ws is re-poisoned each call

    degree_kernel<<<BB * (NMAX / ROWS), 256, 0, stream>>>(
        adj, num_nodes, deg, deg + (size_t)BB * NMAX);

    hist_kernel<<<2 * BB, 256, 0, stream>>>(
        deg, num_nodes, centers, widths, out);
}

// Round 2
// 631.500 us; speedup vs baseline: 1.0085x; 1.0085x over previous
//
#include <hip/hip_runtime.h>

#define NMAX 1024
#define BB   128
#define BINS 64
#define ROWS 32   // rows per block in degree kernel; N/ROWS = 32 chunks per batch

// Per block: one batch b, 32 consecutive rows, 256 threads, thread t owns
// columns 4t..4t+3 (one float4 per row). adj entries are exactly 0.0 or 1.0,
// so row sums are popcounts: per row, 4x (v_cmp -> __ballot) gives wave-uniform
// 64-bit masks; popcount+accumulate runs on the SCALAR pipe (s_bcnt1/s_add),
// leaving the VALU free and removing the 6-deep DS shuffle chain per row.
// Column sums accumulate in 4 private registers across the 32 rows, then
// <=4 global atomicAdds per thread (zero-skipped).
__global__ __launch_bounds__(256) void degree_kernel(
    const float* __restrict__ adj, const int* __restrict__ num_nodes,
    float* __restrict__ in_deg, float* __restrict__ out_deg)
{
    const int b     = blockIdx.x >> 5;   // 32 chunks per batch
    const int chunk = blockIdx.x & 31;
    const int n     = num_nodes[b];
    const int row0  = chunk * ROWS;
    if (row0 >= n) return;               // whole chunk is masked out

    const int t    = threadIdx.x;
    const int lane = t & 63;
    const int wave = t >> 6;
    const int j0   = t * 4;
    const bool act = (j0 < n);           // thread has at least one valid column

    // fold column-validity into the compare threshold: invalid cols never pass
    const float BIG = 3.0e38f;
    const float th0 = (j0 + 0 < n) ? 0.5f : BIG;
    const float th1 = (j0 + 1 < n) ? 0.5f : BIG;
    const float th2 = (j0 + 2 < n) ? 0.5f : BIG;
    const float th3 = (j0 + 3 < n) ? 0.5f : BIG;

    float c0 = 0.f, c1 = 0.f, c2 = 0.f, c3 = 0.f;  // column partial sums

    __shared__ float rowpart[ROWS][4];   // [row_in_chunk][wave]

    const int rows = min(ROWS, n - row0);
    const float4* base = (const float4*)(adj + ((size_t)b * NMAX + row0) * NMAX) + t;

    #pragma unroll 4
    for (int r = 0; r < rows; ++r) {
        float4 v = make_float4(0.f, 0.f, 0.f, 0.f);
        if (act) v = base[r * (NMAX / 4)];        // coalesced 16B/lane
        const bool p0 = v.x > th0;
        const bool p1 = v.y > th1;
        const bool p2 = v.z > th2;
        const bool p3 = v.w > th3;
        c0 += p0 ? 1.f : 0.f;
        c1 += p1 ? 1.f : 0.f;
        c2 += p2 ? 1.f : 0.f;
        c3 += p3 ? 1.f : 0.f;
        const unsigned long long b0 = __ballot(p0);
        const unsigned long long b1 = __ballot(p1);
        const unsigned long long b2 = __ballot(p2);
        const unsigned long long b3 = __ballot(p3);
        const int rs = __popcll(b0) + __popcll(b1) + __popcll(b2) + __popcll(b3);
        if (lane == 0) rowpart[r][wave] = (float)rs;   // wave-uniform value
    }
    __syncthreads();

    if (t < rows) {
        const float s = rowpart[t][0] + rowpart[t][1] + rowpart[t][2] + rowpart[t][3];
        in_deg[b * NMAX + row0 + t] = s;   // unique row per block: plain store
    }

    if (act) {
        float* op = out_deg + b * NMAX + j0;
        if (c0 != 0.f) atomicAdd(op + 0, c0);
        if (c1 != 0.f) atomicAdd(op + 1, c1);
        if (c2 != 0.f) atomicAdd(op + 2, c2);
        if (c3 != 0.f) atomicAdd(op + 3, c3);
    }
}

// One block per (side, b). Triangle kernel with width = 1/spacing has support
// exactly [c_k - spacing, c_k + spacing] -> each degree contributes only to
// bins floor(d/spacing) and floor(d/spacing)+1. Score computed with the exact
// reference formula using the input center/width arrays.
__global__ __launch_bounds__(256) void hist_kernel(
    const float* __restrict__ deg, const int* __restrict__ num_nodes,
    const float* __restrict__ centers, const float* __restrict__ widths,
    float* __restrict__ out)
{
    const int side = blockIdx.x >> 7;    // 0: in_deg, 1: out_deg
    const int b    = blockIdx.x & 127;

    __shared__ float hist[BINS];
    __shared__ float c[BINS];
    __shared__ float w[BINS];
    if (threadIdx.x < BINS) {
        hist[threadIdx.x] = 0.f;
        c[threadIdx.x] = centers[threadIdx.x];
        w[threadIdx.x] = widths[threadIdx.x];
    }
    __syncthreads();

    const int n = num_nodes[b];
    const float inv_sp = w[0];           // 1/spacing (uniform bins)
    const float* dp = deg + ((size_t)side * BB + b) * NMAX;

    for (int i = threadIdx.x; i < n; i += 256) {
        const float d   = dp[i];
        const float pos = d * inv_sp;
        const int   k0  = (int)floorf(pos);
        #pragma unroll
        for (int kk = 0; kk < 2; ++kk) {
            const int k = k0 + kk;
            if (k >= 0 && k < BINS) {
                const float s = 1.f - fabsf(d - c[k]) * w[k];
                if (s > 0.f) atomicAdd(&hist[k], s);
            }
        }
    }
    __syncthreads();

    if (threadIdx.x < BINS)
        out[((size_t)side * BB + b) * BINS + threadIdx.x] = hist[threadIdx.x];
}

extern "C" void kernel_launch(void* const* d_in, const int* in_sizes, int n_in,
                              void* d_out, int out_size, void* d_ws, size_t ws_size,
                              hipStream_t stream) {
    const float* adj       = (const float*)d_in[0];
    const int*   num_nodes = (const int*)d_in[1];
    const float* centers   = (const float*)d_in[2];
    const float* widths    = (const float*)d_in[3];
    float* out = (float*)d_out;

    float* deg = (float*)d_ws;                    // [2][BB][NMAX]: in_deg then out_deg
    float* in_deg  = deg;
    float* out_deg = deg + (size_t)BB * NMAX;

    // only out_deg needs zeroing (atomic accumulation target); in_deg is
    // fully written for every i < n_b, and hist never reads i >= n_b.
    hipMemsetAsync(out_deg, 0, (size_t)BB * NMAX * sizeof(float), stream);

    degree_kernel<<<BB * (NMAX / ROWS), 256, 0, stream>>>(
        adj, num_nodes, in_deg, out_deg);

    hist_kernel<<<2 * BB, 256, 0, stream>>>(
        deg, num_nodes, centers, widths, out);
}